// Round 7
// baseline (220.618 us; speedup 1.0000x reference)
//
#include <hip/hip_runtime.h>
#include <hip/hip_bf16.h>
#include <hip/hip_fp16.h>
#include <cstdint>

#define EMBED 256
#define GPS 8        // groups
#define NCAM 6
#define NLVL 4
#define NPT 13
#define NANC 900
#define NSAMP (NCAM*NLVL*NPT)   // 312
#define NWCOL (GPS*NSAMP)       // 2496
#define MPAD 928                // 29 tiles of 32 rows
#define WSTRIDE 328             // LDS stride for [g][s] weights (conflict-free)
#define MAXENT 352              // 312 -> pad32 (<=320) + 32 overrun slots

// contiguous feature buffer: element base offsets per level
#define FMOFF0 0
#define FMOFF1 17301504            // 6*11264*256
#define FMOFF2 21626880            // +6*2816*256
#define FMOFF3 22708224            // +6*704*256
#define TALL_ELEMS 22978560        // +6*176*256

typedef __attribute__((ext_vector_type(8))) short bf16x8;
typedef __attribute__((ext_vector_type(16))) float f32x16;
typedef __attribute__((ext_vector_type(8))) unsigned short ushort8_t;

__device__ __forceinline__ ushort bf16bits(float x) {
    __hip_bfloat16 h = __float2bfloat16(x);
    return *reinterpret_cast<ushort*>(&h);
}
__device__ __forceinline__ ushort h16bits(float x) {
    __half h = __float2half(x);
    return *reinterpret_cast<ushort*>(&h);
}
__device__ __forceinline__ __half2 u2h2(unsigned u) {
    union { unsigned u; __half2 h; } cv; cv.u = u; return cv.h;
}

// ---------------- K1: fused prep (unchanged) ---------------------------------
__global__ __launch_bounds__(256) void k_prep(
        const float* __restrict__ fm0, const float* __restrict__ fm1,
        const float* __restrict__ fm2, const float* __restrict__ fm3,
        __half* __restrict__ t0, __half* __restrict__ t1,
        __half* __restrict__ t2, __half* __restrict__ t3,
        const float* __restrict__ wlin, __hip_bfloat16* __restrict__ wt,
        const float* __restrict__ inst, const float* __restrict__ anch,
        __hip_bfloat16* __restrict__ featB,
        const float* __restrict__ kp, const float* __restrict__ proj,
        float* __restrict__ pxy) {
    __shared__ ushort lds2[256 * 64];     // 32 KiB, shared by both transposes
    int b = blockIdx.x;
    int t = threadIdx.x;
    if (b < 1404) {
        const float* in; __half* outp; int HW, chunks, lb;
        if (b < 1056)      { in = fm0; outp = t0; HW = 11264; chunks = 176; lb = b; }
        else if (b < 1320) { in = fm1; outp = t1; HW = 2816;  chunks = 44;  lb = b - 1056; }
        else if (b < 1386) { in = fm2; outp = t2; HW = 704;   chunks = 11;  lb = b - 1320; }
        else               { in = fm3; outp = t3; HW = 176;   chunks = 3;   lb = b - 1386; }
        int c = lb / chunks;
        int hw0 = (lb - c * chunks) * 64;
        int q = t & 15, eg = t >> 4;
        bool vld = (hw0 + q * 4 + 3) < HW;
        const float* srcq = in + (size_t)c * EMBED * HW + hw0 + q * 4;
        float4 vals[16];
        #pragma unroll
        for (int r = 0; r < 16; r++) {
            int e = eg + r * 16;
            vals[r] = vld ? *(const float4*)(srcq + (size_t)e * HW)
                          : make_float4(0.f, 0.f, 0.f, 0.f);
        }
        #pragma unroll
        for (int r = 0; r < 16; r++) {
            int e = eg + r * 16;
            int sw = ((e >> 3) & 15) * 4;
            ushort4 u;
            u.x = h16bits(vals[r].x); u.y = h16bits(vals[r].y);
            u.z = h16bits(vals[r].z); u.w = h16bits(vals[r].w);
            *reinterpret_cast<ushort4*>(&lds2[e * 64 + ((q * 4) ^ sw)]) = u;
        }
        __syncthreads();
        ushort* outb = reinterpret_cast<ushort*>(outp) + ((size_t)c * HW + hw0) * EMBED;
        #pragma unroll
        for (int r = 0; r < 8; r++) {
            int flat = r * 2048 + t * 8;
            int hw = flat >> 8;
            int e0 = flat & 255;
            if (hw0 + hw < HW) {
                ushort8_t u;
                #pragma unroll
                for (int j = 0; j < 8; j++) {
                    int e = e0 + j;
                    int sw = ((e >> 3) & 15) * 4;
                    u[j] = lds2[e * 64 + (hw ^ sw)];
                }
                *reinterpret_cast<ushort8_t*>(outb + flat) = u;
            }
        }
    } else if (b < 1560) {
        int b1 = b - 1404;
        int kt = b1 / 39, nt = b1 - kt * 39;
        int k0 = kt * 64, n0 = nt * 64;
        int grp = t >> 6, nn = t & 63;
        #pragma unroll
        for (int r = 0; r < 16; r++) {
            int kk = grp * 16 + r;
            lds2[kk * 65 + nn] = bf16bits(wlin[(size_t)(k0 + kk) * NWCOL + n0 + nn]);
        }
        __syncthreads();
        ushort* wtb = reinterpret_cast<ushort*>(wt);
        int kk2 = t & 63;
        #pragma unroll
        for (int r = 0; r < 16; r++) {
            int nn2 = grp * 16 + r;
            wtb[(size_t)(n0 + nn2) * EMBED + k0 + kk2] = lds2[kk2 * 65 + nn2];
        }
    } else if (b < 1785) {
        int base = (b - 1560) * 1024 + t * 4;
        float4 a = *(const float4*)&inst[base];
        float4 c = *(const float4*)&anch[base];
        ushort4 r;
        r.x = bf16bits(a.x + c.x); r.y = bf16bits(a.y + c.y);
        r.z = bf16bits(a.z + c.z); r.w = bf16bits(a.w + c.w);
        *reinterpret_cast<ushort4*>(reinterpret_cast<ushort*>(featB) + base) = r;
    } else if (b < 1792) {
        int base = 900 * EMBED + (b - 1785) * 1024 + t * 4;
        ushort4 z; z.x = z.y = z.z = z.w = 0;
        *reinterpret_cast<ushort4*>(reinterpret_cast<ushort*>(featB) + base) = z;
    } else {
        int i = (b - 1792) * 256 + t;
        if (i < NANC * NCAM * NPT) {
            int a = i / (NCAM * NPT);
            int r = i - a * (NCAM * NPT);
            int c = r / NPT;
            int p = r - c * NPT;
            const float* M = proj + c * 16;
            const float* k3 = kp + ((size_t)a * NPT + p) * 3;
            float kx = k3[0], ky = k3[1], kz = k3[2];
            float X = M[0] * kx + M[1] * ky + M[2] * kz + M[3];
            float Y = M[4] * kx + M[5] * ky + M[6] * kz + M[7];
            float Z = M[8] * kx + M[9] * ky + M[10] * kz + M[11];
            float invz = 1.f / fmaxf(Z, 1e-5f);
            pxy[(size_t)i * 2 + 0] = X * invz;
            pxy[(size_t)i * 2 + 1] = Y * invz;
        }
    }
}

// ---------------- K2: logits GEMM via MFMA bf16 (unchanged) ------------------
#define MT 29
#define NT 78
__global__ __launch_bounds__(256) void k_gemm(const __hip_bfloat16* __restrict__ featB,
                                              const __hip_bfloat16* __restrict__ wt,
                                              const float* __restrict__ blin,
                                              float* __restrict__ logits) {
    int wv = threadIdx.x >> 6, lane = threadIdx.x & 63;
    int idx = blockIdx.x * 4 + wv;
    if (idx >= MT * NT) return;
    int mt = idx % MT, nt = idx / MT;
    int m0 = mt * 32, n0 = nt * 32;
    int l31 = lane & 31;
    int khalf = (lane >> 5) * 8;
    const short* ap = reinterpret_cast<const short*>(featB) + (size_t)(m0 + l31) * EMBED + khalf;
    const short* bp = reinterpret_cast<const short*>(wt)    + (size_t)(n0 + l31) * EMBED + khalf;
    f32x16 acc = {};
    #pragma unroll 8
    for (int ki = 0; ki < 16; ki++) {
        bf16x8 a = *reinterpret_cast<const bf16x8*>(ap + ki * 16);
        bf16x8 bb = *reinterpret_cast<const bf16x8*>(bp + ki * 16);
        acc = __builtin_amdgcn_mfma_f32_32x32x16_bf16(a, bb, acc, 0, 0, 0);
    }
    float bias = blin[n0 + l31];
    int colg = n0 + l31;
    #pragma unroll
    for (int r = 0; r < 16; r++) {
        int row = (r & 3) + 8 * (r >> 2) + 4 * (lane >> 5);
        int grow = m0 + row;
        if (grow < NANC)
            logits[(size_t)grow * NWCOL + colg] = acc[r] + bias;
    }
}

// ---------------- K3: softmax + compacted gather (depth-4 pipeline) ----------
// Phase A: softmax + per-sample precompute compacted into LDS entry list,
// zero-filled through cnt_pad+32 so the depth-4 refill needs no guards.
// Phase B: 4-entry rotating register pipeline -> 16 gather loads (8 KB/wave)
// in flight; stale over-reads hit offset 0 with weight 0 (harmless).
__global__ __launch_bounds__(512) void k_aggregate(const __half* __restrict__ tAll,
                                                   const float* __restrict__ logits,
                                                   const float* __restrict__ pxy,
                                                   const float* __restrict__ wout,
                                                   const float* __restrict__ bout,
                                                   const float* __restrict__ inst,
                                                   float* __restrict__ out) {
    __shared__ float wT[GPS * WSTRIDE];    // 10496 B
    __shared__ float xyS[NCAM * NPT * 2];  // 624 B
    __shared__ float redS[8][EMBED];       // 8192 B
    __shared__ float pS[EMBED];            // 1024 B
    __shared__ int4  eOff[MAXENT];         // 5632 B
    __shared__ float4 eW[MAXENT];          // 5632 B
    __shared__ int   eS[MAXENT];           // 1408 B
    __shared__ int   cntS;
    int a = blockIdx.x;
    int tid = threadIdx.x;
    int wave = tid >> 6;
    int lane = tid & 63;
    if (tid == 0) cntS = 0;
    for (int j = tid; j < NWCOL; j += 512)
        wT[(j & 7) * WSTRIDE + (j >> 3)] = logits[(size_t)a * NWCOL + j];
    for (int j = tid; j < NCAM * NPT * 2; j += 512)
        xyS[j] = pxy[(size_t)a * NCAM * NPT * 2 + j];
    __syncthreads();
    // ---- softmax: wave g owns group g ----
    {
        int g = wave;
        float m = -1e30f;
        for (int s = lane; s < NSAMP; s += 64) m = fmaxf(m, wT[g * WSTRIDE + s]);
        #pragma unroll
        for (int off = 32; off; off >>= 1) m = fmaxf(m, __shfl_xor(m, off));
        float ssum = 0.f;
        for (int s = lane; s < NSAMP; s += 64) ssum += __expf(wT[g * WSTRIDE + s] - m);
        #pragma unroll
        for (int off = 32; off; off >>= 1) ssum += __shfl_xor(ssum, off);
        float rs = 1.f / ssum;
        for (int s = lane; s < NSAMP; s += 64)
            wT[g * WSTRIDE + s] = __expf(wT[g * WSTRIDE + s] - m) * rs;
    }
    // ---- sample precompute + compaction (threads 0..311, 1 per sample) ----
    {
        bool valid = false; int4 o4; float4 w4;
        if (tid < NSAMP) {
            int c = tid / 52, rem = tid - c * 52;
            int l = rem / 13, p = rem - l * 13;
            float X = xyS[(c * NPT + p) * 2], Y = xyS[(c * NPT + p) * 2 + 1];
            int Wl = 176 >> l, Hl = 64 >> l;
            float scale = 0.25f / (float)(1 << l);
            float gx = fmaf(X, scale, -0.5f);
            float gy = fmaf(Y, scale, -0.5f);
            float x0f = floorf(gx), y0f = floorf(gy);
            float fx = gx - x0f, fy = gy - y0f;
            int x0 = (int)x0f, y0 = (int)y0f;
            int x1 = x0 + 1, y1 = y0 + 1;
            bool vx0 = (x0 >= 0) && (x0 < Wl);
            bool vx1 = (x1 >= 0) && (x1 < Wl);
            bool vy0 = (y0 >= 0) && (y0 < Hl);
            bool vy1 = (y1 >= 0) && (y1 < Hl);
            w4.x = (vx0 && vy0) ? (1.f - fx) * (1.f - fy) : 0.f;
            w4.y = (vx1 && vy0) ? fx * (1.f - fy) : 0.f;
            w4.z = (vx0 && vy1) ? (1.f - fx) * fy : 0.f;
            w4.w = (vx1 && vy1) ? fx * fy : 0.f;
            if (w4.x + w4.y + w4.z + w4.w > 0.f) {
                valid = true;
                int xc0 = min(max(x0, 0), Wl - 1), xc1 = min(max(x1, 0), Wl - 1);
                int yc0 = min(max(y0, 0), Hl - 1), yc1 = min(max(y1, 0), Hl - 1);
                const int lvlBase[4] = { FMOFF0, FMOFF1, FMOFF2, FMOFF3 };
                int cb = lvlBase[l] + c * (Wl * Hl) * EMBED;
                o4.x = cb + (yc0 * Wl + xc0) * EMBED;
                o4.y = cb + (yc0 * Wl + xc1) * EMBED;
                o4.z = cb + (yc1 * Wl + xc0) * EMBED;
                o4.w = cb + (yc1 * Wl + xc1) * EMBED;
            }
        }
        unsigned long long mask = __ballot(valid);
        int prefix = __popcll(mask & ((1ull << lane) - 1ull));
        int wcount = __popcll(mask);
        int basev = 0;
        if (lane == 0 && wcount) basev = atomicAdd(&cntS, wcount);
        basev = __shfl(basev, 0);
        if (valid) {
            int pos = basev + prefix;
            eOff[pos] = o4; eW[pos] = w4; eS[pos] = tid;
        }
    }
    __syncthreads();
    int cnt = cntS;
    int cnt_pad = (cnt + 31) & ~31;
    for (int j = cnt + tid; j < cnt_pad + 32; j += 512) {
        eOff[j] = make_int4(0, 0, 0, 0);
        eW[j] = make_float4(0.f, 0.f, 0.f, 0.f);
        eS[j] = 0;
    }
    __syncthreads();
    // ---- phase B: depth-4 pipelined gather ----
    int e0 = lane * 4;
    int g = lane >> 3;
    float a0 = 0.f, a1 = 0.f, a2 = 0.f, a3 = 0.f;
    {
        float4 w[4]; int si[4];
        uint2 v0[4], v1[4], v2[4], v3[4];
        #pragma unroll
        for (int s = 0; s < 4; s++) {
            int j = wave + 8 * s;
            int4 o = eOff[j]; w[s] = eW[j]; si[s] = eS[j];
            v0[s] = *(const uint2*)(tAll + o.x + e0);
            v1[s] = *(const uint2*)(tAll + o.y + e0);
            v2[s] = *(const uint2*)(tAll + o.z + e0);
            v3[s] = *(const uint2*)(tAll + o.w + e0);
        }
        int per = cnt_pad >> 3;            // entries per wave, multiple of 4
        int j = wave + 32;
        for (int it = 0; it < per; it += 4) {
            #pragma unroll
            for (int s = 0; s < 4; s++) {
                // consume slot s
                {
                    float wg = wT[g * WSTRIDE + si[s]];
                    __half2 W00 = __float2half2_rn(w[s].x), W01 = __float2half2_rn(w[s].y);
                    __half2 W10 = __float2half2_rn(w[s].z), W11 = __float2half2_rn(w[s].w);
                    __half2 blo = __hfma2(u2h2(v0[s].x), W00,
                                  __hfma2(u2h2(v1[s].x), W01,
                                  __hfma2(u2h2(v2[s].x), W10,
                                  __hmul2(u2h2(v3[s].x), W11))));
                    __half2 bhi = __hfma2(u2h2(v0[s].y), W00,
                                  __hfma2(u2h2(v1[s].y), W01,
                                  __hfma2(u2h2(v2[s].y), W10,
                                  __hmul2(u2h2(v3[s].y), W11))));
                    float2 flo = __half22float2(blo);
                    float2 fhi = __half22float2(bhi);
                    a0 = fmaf(wg, flo.x, a0);
                    a1 = fmaf(wg, flo.y, a1);
                    a2 = fmaf(wg, fhi.x, a2);
                    a3 = fmaf(wg, fhi.y, a3);
                }
                // refill slot s for iteration it+4 (zero-filled overrun: no guard)
                {
                    int4 o = eOff[j]; w[s] = eW[j]; si[s] = eS[j];
                    v0[s] = *(const uint2*)(tAll + o.x + e0);
                    v1[s] = *(const uint2*)(tAll + o.y + e0);
                    v2[s] = *(const uint2*)(tAll + o.z + e0);
                    v3[s] = *(const uint2*)(tAll + o.w + e0);
                    j += 8;
                }
            }
        }
    }
    redS[wave][e0 + 0] = a0; redS[wave][e0 + 1] = a1;
    redS[wave][e0 + 2] = a2; redS[wave][e0 + 3] = a3;
    __syncthreads();
    // ---- epilogue: fused @ w_out + b_out + inst ----
    int col = tid & 255;
    int kh = tid >> 8;
    if (kh == 0) {
        float s = redS[0][col] + redS[1][col] + redS[2][col] + redS[3][col]
                + redS[4][col] + redS[5][col] + redS[6][col] + redS[7][col];
        redS[0][col] = s;
    }
    __syncthreads();
    float acc = 0.f;
    int kbase = kh * 128;
    #pragma unroll 8
    for (int k = 0; k < 128; k++)
        acc = fmaf(redS[0][kbase + k], wout[(size_t)(kbase + k) * EMBED + col], acc);
    if (kh == 1) pS[col] = acc;
    __syncthreads();
    if (kh == 0)
        out[(size_t)a * EMBED + col] = acc + pS[col] + bout[col] + inst[(size_t)a * EMBED + col];
}

extern "C" void kernel_launch(void* const* d_in, const int* in_sizes, int n_in,
                              void* d_out, int out_size, void* d_ws, size_t ws_size,
                              hipStream_t stream) {
    const float* inst = (const float*)d_in[0];
    const float* anch = (const float*)d_in[1];
    const float* kp   = (const float*)d_in[2];
    const float* fm0  = (const float*)d_in[3];
    const float* fm1  = (const float*)d_in[4];
    const float* fm2  = (const float*)d_in[5];
    const float* fm3  = (const float*)d_in[6];
    const float* proj = (const float*)d_in[7];
    const float* wlin = (const float*)d_in[9];
    const float* blin = (const float*)d_in[10];
    const float* wout = (const float*)d_in[11];
    const float* bout = (const float*)d_in[12];
    float* out = (float*)d_out;

    char* ws = (char*)d_ws;
    size_t off = 0;
    auto alloc = [&](size_t bytes) -> void* {
        void* p = ws + off;
        off = (off + bytes + 255) & ~(size_t)255;
        return p;
    };
    __half* tAll = (__half*)alloc((size_t)TALL_ELEMS * 2);
    __half* t0 = tAll + FMOFF0;
    __half* t1 = tAll + FMOFF1;
    __half* t2 = tAll + FMOFF2;
    __half* t3 = tAll + FMOFF3;
    __hip_bfloat16* wt    = (__hip_bfloat16*)alloc((size_t)NWCOL * EMBED * 2);
    __hip_bfloat16* featB = (__hip_bfloat16*)alloc((size_t)MPAD * EMBED * 2);
    float* logits = (float*)alloc((size_t)NANC * NWCOL * 4);
    float* pxy    = (float*)alloc((size_t)NANC * NCAM * NPT * 2 * 4);

    k_prep<<<dim3(2067), 256, 0, stream>>>(fm0, fm1, fm2, fm3, t0, t1, t2, t3,
                                           wlin, wt, inst, anch, featB, kp, proj, pxy);
    k_gemm<<<dim3((MT * NT + 3) / 4), 256, 0, stream>>>(featB, wt, blin, logits);
    k_aggregate<<<dim3(NANC), 512, 0, stream>>>(tAll, logits, pxy,
                                                wout, bout, inst, out);
}

// Round 8
// 194.686 us; speedup vs baseline: 1.1332x; 1.1332x over previous
//
#include <hip/hip_runtime.h>
#include <hip/hip_bf16.h>
#include <hip/hip_fp16.h>
#include <cstdint>

#define EMBED 256
#define GPS 8        // groups
#define NCAM 6
#define NLVL 4
#define NPT 13
#define NANC 900
#define NSAMP (NCAM*NLVL*NPT)   // 312
#define NWCOL (GPS*NSAMP)       // 2496
#define MPAD 928                // 29 tiles of 32 rows
#define WSTRIDE 328             // LDS stride for [g][s] weights (conflict-free)
#define MAXENT 352              // pad32 (<=320) + overrun slots

// contiguous fp8 feature buffer: BYTE offsets per level (1 B/elem)
#define FMOFF0 0
#define FMOFF1 17301504            // 6*11264*256
#define FMOFF2 21626880            // +6*2816*256
#define FMOFF3 22708224            // +6*704*256
#define TALL_BYTES 22978560        // +6*176*256

typedef __attribute__((ext_vector_type(8))) short bf16x8;
typedef __attribute__((ext_vector_type(16))) float f32x16;
typedef __attribute__((ext_vector_type(2))) float v2f;

__device__ __forceinline__ ushort bf16bits(float x) {
    __hip_bfloat16 h = __float2bfloat16(x);
    return *reinterpret_cast<ushort*>(&h);
}

// ---------------- K1: fused prep ---------------------------------------------
// fm transpose now emits fp8 e4m3. LDS tile: 128 e-pair rows x 64 hw cols of
// ushort (2 fp8: e,e+1). Swizzle s2(ep)=(ep>>1)&62 keeps phase-2 column reads
// <=2-way bank-conflicted (free) while phase-1 writes uint pairs.
__global__ __launch_bounds__(256) void k_prep(
        const float* __restrict__ fm0, const float* __restrict__ fm1,
        const float* __restrict__ fm2, const float* __restrict__ fm3,
        unsigned char* __restrict__ t0, unsigned char* __restrict__ t1,
        unsigned char* __restrict__ t2, unsigned char* __restrict__ t3,
        const float* __restrict__ wlin, __hip_bfloat16* __restrict__ wt,
        const float* __restrict__ inst, const float* __restrict__ anch,
        __hip_bfloat16* __restrict__ featB,
        const float* __restrict__ kp, const float* __restrict__ proj,
        float* __restrict__ pxy) {
    __shared__ ushort lds2[128 * 64];     // 16 KiB
    int b = blockIdx.x;
    int t = threadIdx.x;
    if (b < 1404) {
        const float* in; unsigned char* outp; int HW, chunks, lb;
        if (b < 1056)      { in = fm0; outp = t0; HW = 11264; chunks = 176; lb = b; }
        else if (b < 1320) { in = fm1; outp = t1; HW = 2816;  chunks = 44;  lb = b - 1056; }
        else if (b < 1386) { in = fm2; outp = t2; HW = 704;   chunks = 11;  lb = b - 1320; }
        else               { in = fm3; outp = t3; HW = 176;   chunks = 3;   lb = b - 1386; }
        int c = lb / chunks;
        int hw0 = (lb - c * chunks) * 64;
        int q = t & 15, eg = t >> 4;
        bool vld = (hw0 + q * 4 + 3) < HW;
        const float* srcq = in + (size_t)c * EMBED * HW + hw0 + q * 4;
        // phase 1: 16 independent loads (e = 2*eg + (r&1) + 32*(r>>1))
        float4 vals[16];
        #pragma unroll
        for (int r = 0; r < 16; r++) {
            int e = 2 * eg + (r & 1) + 32 * (r >> 1);
            vals[r] = vld ? *(const float4*)(srcq + (size_t)e * HW)
                          : make_float4(0.f, 0.f, 0.f, 0.f);
        }
        #pragma unroll
        for (int rp = 0; rp < 8; rp++) {
            int ep = eg + 16 * rp;
            int s2 = (ep >> 1) & 62;
            float4 va = vals[2 * rp], vb = vals[2 * rp + 1];
            uint p0 = (uint)__builtin_amdgcn_cvt_pk_fp8_f32(va.x, vb.x, 0, false) & 0xffff;
            uint p1 = (uint)__builtin_amdgcn_cvt_pk_fp8_f32(va.y, vb.y, 0, false) & 0xffff;
            uint p2 = (uint)__builtin_amdgcn_cvt_pk_fp8_f32(va.z, vb.z, 0, false) & 0xffff;
            uint p3 = (uint)__builtin_amdgcn_cvt_pk_fp8_f32(va.w, vb.w, 0, false) & 0xffff;
            int col01 = (q * 4) ^ s2;
            int col23 = (q * 4 + 2) ^ s2;
            *reinterpret_cast<uint*>(&lds2[ep * 64 + col01]) = p0 | (p1 << 16);
            *reinterpret_cast<uint*>(&lds2[ep * 64 + col23]) = p2 | (p3 << 16);
        }
        __syncthreads();
        // phase 2: linear 8-B stores over the (64hw x 256e) fp8 chunk
        ushort* outb = reinterpret_cast<ushort*>(outp) + ((size_t)c * HW + hw0) * 128;
        #pragma unroll
        for (int r = 0; r < 8; r++) {
            int flat = r * 2048 + t * 8;          // byte index in chunk
            int hw = flat >> 8;
            int ep0 = (flat & 255) >> 1;          // 4*(t&31)
            if (hw0 + hw < HW) {
                ushort4 u;
                #pragma unroll
                for (int j = 0; j < 4; j++) {
                    int ep = ep0 + j;
                    int s2 = (ep >> 1) & 62;
                    u[j] = lds2[ep * 64 + (hw ^ s2)];
                }
                *reinterpret_cast<ushort4*>(outb + flat / 2) = u;
            }
        }
    } else if (b < 1560) {
        // W^T: wt[n][k] = bf16(wlin[k][n]); 64x64 tiles (tile stride 65)
        int b1 = b - 1404;
        int kt = b1 / 39, nt = b1 - kt * 39;
        int k0 = kt * 64, n0 = nt * 64;
        int grp = t >> 6, nn = t & 63;
        #pragma unroll
        for (int r = 0; r < 16; r++) {
            int kk = grp * 16 + r;
            lds2[kk * 65 + nn] = bf16bits(wlin[(size_t)(k0 + kk) * NWCOL + n0 + nn]);
        }
        __syncthreads();
        ushort* wtb = reinterpret_cast<ushort*>(wt);
        int kk2 = t & 63;
        #pragma unroll
        for (int r = 0; r < 16; r++) {
            int nn2 = grp * 16 + r;
            wtb[(size_t)(n0 + nn2) * EMBED + k0 + kk2] = lds2[kk2 * 65 + nn2];
        }
    } else if (b < 1785) {
        int base = (b - 1560) * 1024 + t * 4;
        float4 a = *(const float4*)&inst[base];
        float4 c = *(const float4*)&anch[base];
        ushort4 r;
        r.x = bf16bits(a.x + c.x); r.y = bf16bits(a.y + c.y);
        r.z = bf16bits(a.z + c.z); r.w = bf16bits(a.w + c.w);
        *reinterpret_cast<ushort4*>(reinterpret_cast<ushort*>(featB) + base) = r;
    } else if (b < 1792) {
        int base = 900 * EMBED + (b - 1785) * 1024 + t * 4;
        ushort4 z; z.x = z.y = z.z = z.w = 0;
        *reinterpret_cast<ushort4*>(reinterpret_cast<ushort*>(featB) + base) = z;
    } else {
        int i = (b - 1792) * 256 + t;
        if (i < NANC * NCAM * NPT) {
            int a = i / (NCAM * NPT);
            int r = i - a * (NCAM * NPT);
            int c = r / NPT;
            int p = r - c * NPT;
            const float* M = proj + c * 16;
            const float* k3 = kp + ((size_t)a * NPT + p) * 3;
            float kx = k3[0], ky = k3[1], kz = k3[2];
            float X = M[0] * kx + M[1] * ky + M[2] * kz + M[3];
            float Y = M[4] * kx + M[5] * ky + M[6] * kz + M[7];
            float Z = M[8] * kx + M[9] * ky + M[10] * kz + M[11];
            float invz = 1.f / fmaxf(Z, 1e-5f);
            pxy[(size_t)i * 2 + 0] = X * invz;
            pxy[(size_t)i * 2 + 1] = Y * invz;
        }
    }
}

// ---------------- K2: logits GEMM via MFMA bf16 (unchanged) ------------------
#define MT 29
#define NT 78
__global__ __launch_bounds__(256) void k_gemm(const __hip_bfloat16* __restrict__ featB,
                                              const __hip_bfloat16* __restrict__ wt,
                                              const float* __restrict__ blin,
                                              float* __restrict__ logits) {
    int wv = threadIdx.x >> 6, lane = threadIdx.x & 63;
    int idx = blockIdx.x * 4 + wv;
    if (idx >= MT * NT) return;
    int mt = idx % MT, nt = idx / MT;
    int m0 = mt * 32, n0 = nt * 32;
    int l31 = lane & 31;
    int khalf = (lane >> 5) * 8;
    const short* ap = reinterpret_cast<const short*>(featB) + (size_t)(m0 + l31) * EMBED + khalf;
    const short* bp = reinterpret_cast<const short*>(wt)    + (size_t)(n0 + l31) * EMBED + khalf;
    f32x16 acc = {};
    #pragma unroll 8
    for (int ki = 0; ki < 16; ki++) {
        bf16x8 a = *reinterpret_cast<const bf16x8*>(ap + ki * 16);
        bf16x8 bb = *reinterpret_cast<const bf16x8*>(bp + ki * 16);
        acc = __builtin_amdgcn_mfma_f32_32x32x16_bf16(a, bb, acc, 0, 0, 0);
    }
    float bias = blin[n0 + l31];
    int colg = n0 + l31;
    #pragma unroll
    for (int r = 0; r < 16; r++) {
        int row = (r & 3) + 8 * (r >> 2) + 4 * (lane >> 5);
        int grow = m0 + row;
        if (grow < NANC)
            logits[(size_t)grow * NWCOL + colg] = acc[r] + bias;
    }
}

// ---------------- K3: softmax + compacted fp8 gather (depth-2 pipeline) ------
__global__ __launch_bounds__(512) void k_aggregate(const unsigned char* __restrict__ tAll,
                                                   const float* __restrict__ logits,
                                                   const float* __restrict__ pxy,
                                                   const float* __restrict__ wout,
                                                   const float* __restrict__ bout,
                                                   const float* __restrict__ inst,
                                                   float* __restrict__ out) {
    __shared__ float wT[GPS * WSTRIDE];    // 10496 B
    __shared__ float xyS[NCAM * NPT * 2];  // 624 B
    __shared__ float redS[8][EMBED];       // 8192 B
    __shared__ float pS[EMBED];            // 1024 B
    __shared__ int4  eOff[MAXENT];         // 5632 B
    __shared__ float4 eW[MAXENT];          // 5632 B
    __shared__ int   eS[MAXENT];           // 1408 B
    __shared__ int   cntS;
    int a = blockIdx.x;
    int tid = threadIdx.x;
    int wave = tid >> 6;
    int lane = tid & 63;
    if (tid == 0) cntS = 0;
    for (int j = tid; j < NWCOL; j += 512)
        wT[(j & 7) * WSTRIDE + (j >> 3)] = logits[(size_t)a * NWCOL + j];
    for (int j = tid; j < NCAM * NPT * 2; j += 512)
        xyS[j] = pxy[(size_t)a * NCAM * NPT * 2 + j];
    __syncthreads();
    // ---- softmax: wave g owns group g ----
    {
        int g = wave;
        float m = -1e30f;
        for (int s = lane; s < NSAMP; s += 64) m = fmaxf(m, wT[g * WSTRIDE + s]);
        #pragma unroll
        for (int off = 32; off; off >>= 1) m = fmaxf(m, __shfl_xor(m, off));
        float ssum = 0.f;
        for (int s = lane; s < NSAMP; s += 64) ssum += __expf(wT[g * WSTRIDE + s] - m);
        #pragma unroll
        for (int off = 32; off; off >>= 1) ssum += __shfl_xor(ssum, off);
        float rs = 1.f / ssum;
        for (int s = lane; s < NSAMP; s += 64)
            wT[g * WSTRIDE + s] = __expf(wT[g * WSTRIDE + s] - m) * rs;
    }
    // ---- sample precompute + compaction ----
    {
        bool valid = false; int4 o4; float4 w4;
        if (tid < NSAMP) {
            int c = tid / 52, rem = tid - c * 52;
            int l = rem / 13, p = rem - l * 13;
            float X = xyS[(c * NPT + p) * 2], Y = xyS[(c * NPT + p) * 2 + 1];
            int Wl = 176 >> l, Hl = 64 >> l;
            float scale = 0.25f / (float)(1 << l);
            float gx = fmaf(X, scale, -0.5f);
            float gy = fmaf(Y, scale, -0.5f);
            float x0f = floorf(gx), y0f = floorf(gy);
            float fx = gx - x0f, fy = gy - y0f;
            int x0 = (int)x0f, y0 = (int)y0f;
            int x1 = x0 + 1, y1 = y0 + 1;
            bool vx0 = (x0 >= 0) && (x0 < Wl);
            bool vx1 = (x1 >= 0) && (x1 < Wl);
            bool vy0 = (y0 >= 0) && (y0 < Hl);
            bool vy1 = (y1 >= 0) && (y1 < Hl);
            w4.x = (vx0 && vy0) ? (1.f - fx) * (1.f - fy) : 0.f;
            w4.y = (vx1 && vy0) ? fx * (1.f - fy) : 0.f;
            w4.z = (vx0 && vy1) ? (1.f - fx) * fy : 0.f;
            w4.w = (vx1 && vy1) ? fx * fy : 0.f;
            if (w4.x + w4.y + w4.z + w4.w > 0.f) {
                valid = true;
                int xc0 = min(max(x0, 0), Wl - 1), xc1 = min(max(x1, 0), Wl - 1);
                int yc0 = min(max(y0, 0), Hl - 1), yc1 = min(max(y1, 0), Hl - 1);
                const int lvlBase[4] = { FMOFF0, FMOFF1, FMOFF2, FMOFF3 };
                int cb = lvlBase[l] + c * (Wl * Hl) * EMBED;
                o4.x = cb + (yc0 * Wl + xc0) * EMBED;
                o4.y = cb + (yc0 * Wl + xc1) * EMBED;
                o4.z = cb + (yc1 * Wl + xc0) * EMBED;
                o4.w = cb + (yc1 * Wl + xc1) * EMBED;
            }
        }
        unsigned long long mask = __ballot(valid);
        int prefix = __popcll(mask & ((1ull << lane) - 1ull));
        int wcount = __popcll(mask);
        int basev = 0;
        if (lane == 0 && wcount) basev = atomicAdd(&cntS, wcount);
        basev = __shfl(basev, 0);
        if (valid) {
            int pos = basev + prefix;
            eOff[pos] = o4; eW[pos] = w4; eS[pos] = tid;
        }
    }
    __syncthreads();
    int cnt = cntS;
    int cnt_pad = (cnt + 15) & ~15;
    for (int j = cnt + tid; j < cnt_pad + 16; j += 512) {
        eOff[j] = make_int4(0, 0, 0, 0);
        eW[j] = make_float4(0.f, 0.f, 0.f, 0.f);
        eS[j] = 0;
    }
    __syncthreads();
    // ---- phase B: depth-2 pipelined fp8 gather ----
    int e0 = lane * 4;           // byte offset (4 channels)
    int g = lane >> 3;
    float a0 = 0.f, a1 = 0.f, a2 = 0.f, a3 = 0.f;
    auto consume = [&](const float4& w, int sIdx,
                       uint c00, uint c01, uint c10, uint c11) {
        float wg = wT[g * WSTRIDE + sIdx];
        float wwx = wg * w.x, wwy = wg * w.y, wwz = wg * w.z, www = wg * w.w;
        v2f l00 = __builtin_amdgcn_cvt_pk_f32_fp8(c00, false);
        v2f h00 = __builtin_amdgcn_cvt_pk_f32_fp8(c00, true);
        v2f l01 = __builtin_amdgcn_cvt_pk_f32_fp8(c01, false);
        v2f h01 = __builtin_amdgcn_cvt_pk_f32_fp8(c01, true);
        v2f l10 = __builtin_amdgcn_cvt_pk_f32_fp8(c10, false);
        v2f h10 = __builtin_amdgcn_cvt_pk_f32_fp8(c10, true);
        v2f l11 = __builtin_amdgcn_cvt_pk_f32_fp8(c11, false);
        v2f h11 = __builtin_amdgcn_cvt_pk_f32_fp8(c11, true);
        a0 = fmaf(wwx, l00.x, fmaf(wwy, l01.x, fmaf(wwz, l10.x, fmaf(www, l11.x, a0))));
        a1 = fmaf(wwx, l00.y, fmaf(wwy, l01.y, fmaf(wwz, l10.y, fmaf(www, l11.y, a1))));
        a2 = fmaf(wwx, h00.x, fmaf(wwy, h01.x, fmaf(wwz, h10.x, fmaf(www, h11.x, a2))));
        a3 = fmaf(wwx, h00.y, fmaf(wwy, h01.y, fmaf(wwz, h10.y, fmaf(www, h11.y, a3))));
    };
    int per = cnt_pad >> 3;                 // entries per wave (even)
    if (per > 0) {
        int idx = wave;
        int4 oA = eOff[idx]; float4 wA = eW[idx]; int sA = eS[idx];
        uint vA0 = *(const uint*)(tAll + oA.x + e0);
        uint vA1 = *(const uint*)(tAll + oA.y + e0);
        uint vA2 = *(const uint*)(tAll + oA.z + e0);
        uint vA3 = *(const uint*)(tAll + oA.w + e0);
        for (int it = 0; it < per; it += 2) {
            int j = idx + 8;
            int4 oB = eOff[j]; float4 wB = eW[j]; int sB = eS[j];
            uint vB0 = *(const uint*)(tAll + oB.x + e0);
            uint vB1 = *(const uint*)(tAll + oB.y + e0);
            uint vB2 = *(const uint*)(tAll + oB.z + e0);
            uint vB3 = *(const uint*)(tAll + oB.w + e0);
            consume(wA, sA, vA0, vA1, vA2, vA3);
            idx = j + 8;
            if (it + 2 < per) {
                oA = eOff[idx]; wA = eW[idx]; sA = eS[idx];
                vA0 = *(const uint*)(tAll + oA.x + e0);
                vA1 = *(const uint*)(tAll + oA.y + e0);
                vA2 = *(const uint*)(tAll + oA.z + e0);
                vA3 = *(const uint*)(tAll + oA.w + e0);
            }
            consume(wB, sB, vB0, vB1, vB2, vB3);
        }
    }
    redS[wave][e0 + 0] = a0; redS[wave][e0 + 1] = a1;
    redS[wave][e0 + 2] = a2; redS[wave][e0 + 3] = a3;
    __syncthreads();
    // ---- epilogue: fused @ w_out + b_out + inst ----
    int col = tid & 255;
    int kh = tid >> 8;
    if (kh == 0) {
        float s = redS[0][col] + redS[1][col] + redS[2][col] + redS[3][col]
                + redS[4][col] + redS[5][col] + redS[6][col] + redS[7][col];
        redS[0][col] = s;
    }
    __syncthreads();
    float acc = 0.f;
    int kbase = kh * 128;
    #pragma unroll 8
    for (int k = 0; k < 128; k++)
        acc = fmaf(redS[0][kbase + k], wout[(size_t)(kbase + k) * EMBED + col], acc);
    if (kh == 1) pS[col] = acc;
    __syncthreads();
    if (kh == 0)
        out[(size_t)a * EMBED + col] = acc + pS[col] + bout[col] + inst[(size_t)a * EMBED + col];
}

extern "C" void kernel_launch(void* const* d_in, const int* in_sizes, int n_in,
                              void* d_out, int out_size, void* d_ws, size_t ws_size,
                              hipStream_t stream) {
    const float* inst = (const float*)d_in[0];
    const float* anch = (const float*)d_in[1];
    const float* kp   = (const float*)d_in[2];
    const float* fm0  = (const float*)d_in[3];
    const float* fm1  = (const float*)d_in[4];
    const float* fm2  = (const float*)d_in[5];
    const float* fm3  = (const float*)d_in[6];
    const float* proj = (const float*)d_in[7];
    const float* wlin = (const float*)d_in[9];
    const float* blin = (const float*)d_in[10];
    const float* wout = (const float*)d_in[11];
    const float* bout = (const float*)d_in[12];
    float* out = (float*)d_out;

    char* ws = (char*)d_ws;
    size_t off = 0;
    auto alloc = [&](size_t bytes) -> void* {
        void* p = ws + off;
        off = (off + bytes + 255) & ~(size_t)255;
        return p;
    };
    unsigned char* tAll = (unsigned char*)alloc((size_t)TALL_BYTES);
    unsigned char* t0 = tAll + FMOFF0;
    unsigned char* t1 = tAll + FMOFF1;
    unsigned char* t2 = tAll + FMOFF2;
    unsigned char* t3 = tAll + FMOFF3;
    __hip_bfloat16* wt    = (__hip_bfloat16*)alloc((size_t)NWCOL * EMBED * 2);
    __hip_bfloat16* featB = (__hip_bfloat16*)alloc((size_t)MPAD * EMBED * 2);
    float* logits = (float*)alloc((size_t)NANC * NWCOL * 4);
    float* pxy    = (float*)alloc((size_t)NANC * NCAM * NPT * 2 * 4);

    k_prep<<<dim3(2067), 256, 0, stream>>>(fm0, fm1, fm2, fm3, t0, t1, t2, t3,
                                           wlin, wt, inst, anch, featB, kp, proj, pxy);
    k_gemm<<<dim3((MT * NT + 3) / 4), 256, 0, stream>>>(featB, wt, blin, logits);
    k_aggregate<<<dim3(NANC), 512, 0, stream>>>(tAll, logits, pxy,
                                                wout, bout, inst, out);
}